// Round 7
// baseline (276.038 us; speedup 1.0000x reference)
//
#include <hip/hip_runtime.h>
#include <hip/hip_bf16.h>

#define N_NODES 8192
#define E_EDGES 65536
#define HEADS 3
#define CDIM 384
#define NHC 1152
#define T_STEPS 12
#define D_IN 16
#define HID 32
#define PRED_LEN 6
#define OUT_LABEL_OFF 49152   // N_NODES*PRED_LEN elements

#define O_X        0u
#define O_WIH      1572864u
#define O_WHH      1574400u
#define O_BIH      1577472u
#define O_BHH      1577568u
#define O_WGAT     1577664u
#define O_ATTS     2020032u
#define O_ATTD     2021184u
#define O_WEDGE    2022336u
#define O_ATTE     2023488u
#define O_GBIAS    2024640u
#define O_WP1      2025024u
#define O_BP1      2025056u
#define O_WP3      2025057u
#define O_BP3      2025129u
#define O_WC1      2025135u
#define O_BC1      2037423u
#define O_WC2      2037455u
#define O_BC2      2037519u
#define O_EATTR    2037521u
#define CONV_TOTAL 2103057u

#define O_GATIN    2103072u
#define O_GATB     O_GATIN               // bf16 gat_in [N,384]
#define O_WGATB    (O_GATIN + 1572864u)  // bf16 Wgat [1152,384]
#define O_DEG      (O_GATIN + 1794048u)  // int [8192]
#define O_ROWST    (O_GATIN + 1802240u)  // int [8192]
#define O_CURS     (O_GATIN + 1810432u)  // int [8192]
#define O_CSRE     (O_GATIN + 1818624u)  // int [65536]
#define O_HFEAT    5248800u              // bf16 h_feat [N,1152]
#define O_ASRC     14685984u
#define O_ADST     14710560u
#define O_ARAW     14735136u
#define O_WEXP     14931744u
#define O_AMAX     15128352u
#define O_DENOM    15152928u
#define O_GMEAN    15177504u
#define O_POOLED   18323232u
#define O_KH       18326304u
#define O_FLAG     18326307u

typedef __attribute__((ext_vector_type(8))) short short8;
typedef __attribute__((ext_vector_type(4))) float floatx4;

__device__ __forceinline__ float b2f(unsigned short u) {
    return __uint_as_float(((unsigned)u) << 16);
}
__device__ __forceinline__ unsigned short f2b(float f) {
    __hip_bfloat16 b = __float2bfloat16(f);
    return *(unsigned short*)&b;
}
__device__ __forceinline__ unsigned enc_f(float f) {
    unsigned u = __float_as_uint(f);
    return (u & 0x80000000u) ? ~u : (u | 0x80000000u);
}
__device__ __forceinline__ float dec_f(unsigned e) {
    return __uint_as_float((e & 0x80000000u) ? (e & 0x7FFFFFFFu) : ~e);
}
__device__ __forceinline__ float fast_rcp(float x) {
    return __builtin_amdgcn_rcpf(x);
}

// ------------------------------------------------ fill (zero regions) + dtype detect
__global__ __launch_bounds__(256) void fill_detect(
    const unsigned short* __restrict__ wih_raw,
    int* __restrict__ flag,
    float* __restrict__ W)
{
    if (blockIdx.x == 0 && threadIdx.x < 64) {
        int lane = threadIdx.x;
        int cnt = 0;
#pragma unroll
        for (int i = 0; i < 8; i++) {
            unsigned short h = wih_raw[(lane * 8 + i) * 2];
            int e = (h >> 7) & 0xFF;
            if (e >= 100 && e <= 127) cnt++;
        }
#pragma unroll
        for (int off = 32; off; off >>= 1) cnt += __shfl_down(cnt, off, 64);
        if (lane == 0) *flag = (cnt >= 300) ? 1 : 0;
    }
    unsigned idx = blockIdx.x * 256 + threadIdx.x;
    if      (idx < 24576u) W[O_AMAX  + idx] = 0.f;
    else if (idx < 49152u) W[O_DENOM + idx - 24576u] = 0.f;
    else if (idx < 52224u) W[O_POOLED + idx - 49152u] = 0.f;
    else if (idx < 60416u) ((int*)(W + O_DEG))[idx - 52224u] = 0;
}

// ------------------------------------------------ convert all inputs; Wgat branch emits bf16
__global__ __launch_bounds__(256) void convert_all(
    const int* __restrict__ flag,
    const void* x, const void* Wih, const void* Whh, const void* bih, const void* bhh,
    const void* Wgat, const void* atts, const void* attd, const void* Wedge, const void* atte,
    const void* gbias, const void* Wp1, const void* bp1, const void* Wp3, const void* bp3,
    const void* Wc1, const void* bc1, const void* Wc2, const void* bc2, const void* eattr,
    float* __restrict__ dst, unsigned short* __restrict__ wgatb)
{
    unsigned idx = blockIdx.x * 256 + threadIdx.x;
    if (idx >= CONV_TOTAL) return;
    if (idx >= O_WGAT && idx < O_ATTS) {
        unsigned off = idx - O_WGAT;
        wgatb[off] = (*flag) ? ((const unsigned short*)Wgat)[off]
                             : f2b(((const float*)Wgat)[off]);
        return;
    }
    const void* src; unsigned off;
    if      (idx < O_WIH)   { src = x;     off = idx - O_X; }
    else if (idx < O_WHH)   { src = Wih;   off = idx - O_WIH; }
    else if (idx < O_BIH)   { src = Whh;   off = idx - O_WHH; }
    else if (idx < O_BHH)   { src = bih;   off = idx - O_BIH; }
    else if (idx < O_WGAT)  { src = bhh;   off = idx - O_BHH; }
    else if (idx < O_ATTD)  { src = atts;  off = idx - O_ATTS; }
    else if (idx < O_WEDGE) { src = attd;  off = idx - O_ATTD; }
    else if (idx < O_ATTE)  { src = Wedge; off = idx - O_WEDGE; }
    else if (idx < O_GBIAS) { src = atte;  off = idx - O_ATTE; }
    else if (idx < O_WP1)   { src = gbias; off = idx - O_GBIAS; }
    else if (idx < O_BP1)   { src = Wp1;   off = idx - O_WP1; }
    else if (idx < O_BP3)   { src = (idx == O_BP1) ? bp1 : Wp3; off = (idx == O_BP1) ? 0 : idx - O_WP3; }
    else if (idx < O_WC1)   { src = bp3;   off = idx - O_BP3; }
    else if (idx < O_BC1)   { src = Wc1;   off = idx - O_WC1; }
    else if (idx < O_WC2)   { src = bc1;   off = idx - O_BC1; }
    else if (idx < O_BC2)   { src = Wc2;   off = idx - O_WC2; }
    else if (idx < O_EATTR) { src = bc2;   off = idx - O_BC2; }
    else                    { src = eattr; off = idx - O_EATTR; }
    float v = (*flag) ? b2f(((const unsigned short*)src)[off])
                      : ((const float*)src)[off];
    dst[idx] = v;
}

// ------------------------------------------------ GRU: 96 threads/node (one per gate row)
// Each thread holds only 48 weight floats -> guaranteed register-resident
// (R4/R6 evidence: 32-thread/node layout needed ~150 regs, allocator capped at
// ~128 and re-loaded weights every step -> 43 us). Gate combine on g==0 threads
// with fast transcendentals. 2 barriers/timestep.
#define GNODES 4
__global__ __launch_bounds__(384) void gru_kernel(
    const float* __restrict__ xf,
    const float* __restrict__ Wih,
    const float* __restrict__ Whh,
    const float* __restrict__ bih,
    const float* __restrict__ bhh,
    unsigned short* __restrict__ gat_b)   // [N,384] bf16
{
    __shared__ float xsh[GNODES][192];
    __shared__ float hsh[GNODES][32];
    __shared__ float g0s[GNODES][32];   // r preact
    __shared__ float g1s[GNODES][32];   // z preact
    __shared__ float g2i[GNODES][32];   // n: ih part
    __shared__ float g2h[GNODES][32];   // n: hh part

    int tid = threadIdx.x;
    int nl = tid / 96;          // 0..3
    int r96 = tid - nl * 96;    // 0..95
    int g = r96 >> 5, jj = r96 & 31;
    int n = blockIdx.x * GNODES + nl;
    int row = g * 32 + jj;

    float wih[16], whh[32];
#pragma unroll
    for (int i = 0; i < 16; i++) wih[i] = Wih[row * 16 + i];
#pragma unroll
    for (int i = 0; i < 32; i++) whh[i] = Whh[row * 32 + i];
    float bi = bih[row], bh = bhh[row];

    // stage x for this node
    const float* xrow = xf + (size_t)n * 192;
    xsh[nl][r96]      = xrow[r96];
    xsh[nl][r96 + 96] = xrow[r96 + 96];
    if (g == 0) hsh[nl][jj] = 0.f;
    float hval = 0.f;   // live in g==0 threads
    __syncthreads();

    for (int t = 0; t < T_STEPS; t++) {
        // gate pre-activations
        float gi = bi;
#pragma unroll
        for (int q = 0; q < 4; q++) {
            float4 xv = *(const float4*)&xsh[nl][t * 16 + q * 4];
            gi += wih[q*4+0]*xv.x + wih[q*4+1]*xv.y + wih[q*4+2]*xv.z + wih[q*4+3]*xv.w;
        }
        float gh = bh;
#pragma unroll
        for (int q = 0; q < 8; q++) {
            float4 hv = *(const float4*)&hsh[nl][q * 4];
            gh += whh[q*4+0]*hv.x + whh[q*4+1]*hv.y + whh[q*4+2]*hv.z + whh[q*4+3]*hv.w;
        }
        if (g == 0)      g0s[nl][jj] = gi + gh;
        else if (g == 1) g1s[nl][jj] = gi + gh;
        else             { g2i[nl][jj] = gi; g2h[nl][jj] = gh; }
        __syncthreads();

        if (g == 0) {
            float r = fast_rcp(1.f + __expf(-g0s[nl][jj]));
            float z = fast_rcp(1.f + __expf(-g1s[nl][jj]));
            float pre = g2i[nl][jj] + r * g2h[nl][jj];
            float e2 = __expf(2.f * pre);
            float nn = 1.f - 2.f * fast_rcp(e2 + 1.f);   // tanh(pre)
            hval = (1.f - z) * nn + z * hval;
            hsh[nl][jj] = hval;
            gat_b[(size_t)n * 384 + t * 32 + jj] = f2b(hval);
        }
        __syncthreads();
    }
}

// ------------------------------------------------ MFMA GEMM, bf16 output
__global__ __launch_bounds__(256) void gemm_mfma(
    const unsigned short* __restrict__ Ab,
    const unsigned short* __restrict__ Bb,
    unsigned short* __restrict__ Cb)
{
    __shared__ unsigned short sA[128][40];
    __shared__ unsigned short sB[128][40];
    int tid = threadIdx.x;
    int wave = tid >> 6, lane = tid & 63;
    int wm = (wave >> 1) * 64, wn = (wave & 1) * 64;
    int m0 = blockIdx.x * 128, n0 = blockIdx.y * 128;

    int r0 = tid >> 2;
    int c8 = (tid & 3) * 8;

    floatx4 acc[4][4];
#pragma unroll
    for (int i = 0; i < 4; i++)
#pragma unroll
        for (int j = 0; j < 4; j++) acc[i][j] = 0;

    int ml = lane & 15, kq = (lane >> 4) * 8;

    for (int k0 = 0; k0 < 384; k0 += 32) {
        short8 a0 = *(const short8*)(Ab + (size_t)(m0 + r0) * 384 + k0 + c8);
        short8 a1 = *(const short8*)(Ab + (size_t)(m0 + r0 + 64) * 384 + k0 + c8);
        short8 b0 = *(const short8*)(Bb + (size_t)(n0 + r0) * 384 + k0 + c8);
        short8 b1 = *(const short8*)(Bb + (size_t)(n0 + r0 + 64) * 384 + k0 + c8);

        __syncthreads();
        *(short8*)(&sA[r0][c8])      = a0;
        *(short8*)(&sA[r0 + 64][c8]) = a1;
        *(short8*)(&sB[r0][c8])      = b0;
        *(short8*)(&sB[r0 + 64][c8]) = b1;
        __syncthreads();

        short8 af[4], bf[4];
#pragma unroll
        for (int i = 0; i < 4; i++)
            af[i] = *(const short8*)(&sA[wm + i * 16 + ml][kq]);
#pragma unroll
        for (int j = 0; j < 4; j++)
            bf[j] = *(const short8*)(&sB[wn + j * 16 + ml][kq]);
#pragma unroll
        for (int i = 0; i < 4; i++)
#pragma unroll
            for (int j = 0; j < 4; j++)
                acc[i][j] = __builtin_amdgcn_mfma_f32_16x16x32_bf16(af[i], bf[j], acc[i][j], 0, 0, 0);
    }

    int cn = lane & 15, rq = (lane >> 4) * 4;
#pragma unroll
    for (int i = 0; i < 4; i++)
#pragma unroll
        for (int j = 0; j < 4; j++)
#pragma unroll
            for (int r = 0; r < 4; r++)
                Cb[(size_t)(m0 + wm + i * 16 + rq + r) * NHC + n0 + wn + j * 16 + cn] = f2b(acc[i][j][r]);
}

// ------------------------------------------------ node attention scores (+ Kh in extra block)
__global__ __launch_bounds__(256) void att_score_kernel(
    const unsigned short* __restrict__ h_bf,
    const float* __restrict__ att_src,
    const float* __restrict__ att_dst,
    const float* __restrict__ Wedge,
    const float* __restrict__ att_edge,
    float* __restrict__ a_src, float* __restrict__ a_dst,
    float* __restrict__ Kh)
{
    if (blockIdx.x == (N_NODES * 3) / 4) {
        if (threadIdx.x < 192) {
            int hd = threadIdx.x >> 6, lane = threadIdx.x & 63;
            float s = 0.f;
#pragma unroll
            for (int q = 0; q < 6; q++) {
                int c = lane + q * 64;
                s += Wedge[hd * CDIM + c] * att_edge[hd * CDIM + c];
            }
#pragma unroll
            for (int off = 32; off; off >>= 1) s += __shfl_down(s, off, 64);
            if (lane == 0) Kh[hd] = s;
        }
        return;
    }
    int w = (blockIdx.x * 256 + threadIdx.x) >> 6;
    int lane = threadIdx.x & 63;
    int n = w / 3, hd = w % 3;
    const unsigned short* hrow = h_bf + (size_t)n * NHC + hd * CDIM;
    float s0 = 0.f, s1 = 0.f;
#pragma unroll
    for (int q = 0; q < 6; q++) {
        int c = lane + q * 64;
        float hv = b2f(hrow[c]);
        s0 += hv * att_src[hd * CDIM + c];
        s1 += hv * att_dst[hd * CDIM + c];
    }
#pragma unroll
    for (int off = 32; off; off >>= 1) {
        s0 += __shfl_down(s0, off, 64);
        s1 += __shfl_down(s1, off, 64);
    }
    if (lane == 0) { a_src[n * 3 + hd] = s0; a_dst[n * 3 + hd] = s1; }
}

__global__ __launch_bounds__(256) void edge_score_kernel(
    const int* __restrict__ edge_index,
    const float* __restrict__ edge_attr,
    const float* __restrict__ a_src, const float* __restrict__ a_dst,
    const float* __restrict__ Kh,
    float* __restrict__ a_raw, unsigned* __restrict__ amax_enc,
    int* __restrict__ deg)
{
    int tid = blockIdx.x * 256 + threadIdx.x;
    int hd = tid >> 16;
    int e = tid & (E_EDGES - 1);
    int src = edge_index[e];
    int dst = edge_index[E_EDGES + e];
    float a = a_src[src * 3 + hd] + a_dst[dst * 3 + hd] + edge_attr[e] * Kh[hd];
    a = a > 0.f ? a : 0.2f * a;
    a_raw[hd * E_EDGES + e] = a;
    atomicMax(&amax_enc[dst * 3 + hd], enc_f(a));
    if (hd == 0) atomicAdd(&deg[dst], 1);
}

// parallel exclusive scan of deg[8192] (single block, shfl_up wave scans)
__global__ __launch_bounds__(256) void scan_kernel(
    const int* __restrict__ deg, int* __restrict__ rowstart, int* __restrict__ cursor)
{
    __shared__ int wtot[4];
    int t = threadIdx.x;
    int lane = t & 63, wv = t >> 6;
    int l[32], s = 0;
#pragma unroll
    for (int i = 0; i < 32; i++) { l[i] = deg[t * 32 + i]; s += l[i]; }
    int sc = s;
#pragma unroll
    for (int off = 1; off <= 32; off <<= 1) {
        int v = __shfl_up(sc, off, 64);
        if (lane >= off) sc += v;
    }
    if (lane == 63) wtot[wv] = sc;
    __syncthreads();
    int woff = 0;
#pragma unroll
    for (int w = 0; w < 4; w++) if (w < wv) woff += wtot[w];
    int b = woff + sc - s;
#pragma unroll
    for (int i = 0; i < 32; i++) {
        rowstart[t * 32 + i] = b;
        cursor[t * 32 + i] = b;
        b += l[i];
    }
}

__global__ __launch_bounds__(256) void edge_exp_kernel(
    const int* __restrict__ edge_index,
    const float* __restrict__ a_raw, const unsigned* __restrict__ amax_enc,
    float* __restrict__ w_exp, float* __restrict__ denom,
    int* __restrict__ cursor, int* __restrict__ csr_e)
{
    int tid = blockIdx.x * 256 + threadIdx.x;
    int hd = tid >> 16;
    int e = tid & (E_EDGES - 1);
    int dst = edge_index[E_EDGES + e];
    float m = dec_f(amax_enc[dst * 3 + hd]);
    float w = expf(a_raw[hd * E_EDGES + e] - m);
    w_exp[hd * E_EDGES + e] = w;
    unsafeAtomicAdd(&denom[dst * 3 + hd], w);
    if (hd == 0) {
        int pos = atomicAdd(&cursor[dst], 1);
        csr_e[pos] = e;
    }
}

// CSR aggregation fused with head-mean+bias, predictor MLP, out_pred write.
__global__ __launch_bounds__(384) void aggregate_fused(
    const int* __restrict__ flag,
    const int* __restrict__ edge_index,
    const unsigned short* __restrict__ h_bf,
    const float* __restrict__ w_exp, const float* __restrict__ denom,
    const int* __restrict__ rowstart, const int* __restrict__ deg,
    const int* __restrict__ csr_e,
    const float* __restrict__ gat_bias,
    const float* __restrict__ Wp1, const float* __restrict__ bp1,
    const float* __restrict__ Wp3, const float* __restrict__ bp3,
    float* __restrict__ gmean,
    void* __restrict__ out_pred)
{
    int dst = blockIdx.x;
    int s = rowstart[dst], d = deg[dst];
    int tid = threadIdx.x;
    const float third = 1.f / 3.f;
    float inv0 = third / (denom[dst * 3 + 0] + 1e-16f);
    float inv1 = third / (denom[dst * 3 + 1] + 1e-16f);
    float inv2 = third / (denom[dst * 3 + 2] + 1e-16f);
    __shared__ int ssrc[64];
    __shared__ float sc0[64], sc1[64], sc2[64];
    __shared__ float gs[384];
    __shared__ float ps[12];
    float a = 0.f;
    for (int ch = 0; ch < d; ch += 64) {
        int m = d - ch; if (m > 64) m = 64;
        __syncthreads();
        if (tid < m) {
            int e = csr_e[s + ch + tid];
            ssrc[tid] = edge_index[e];
            sc0[tid] = w_exp[e] * inv0;
            sc1[tid] = w_exp[E_EDGES + e] * inv1;
            sc2[tid] = w_exp[2 * E_EDGES + e] * inv2;
        }
        __syncthreads();
        for (int i = 0; i < m; i++) {
            const unsigned short* hs = h_bf + (size_t)ssrc[i] * NHC;
            a += sc0[i] * b2f(hs[tid]) + sc1[i] * b2f(hs[tid + CDIM]) + sc2[i] * b2f(hs[tid + 2 * CDIM]);
        }
    }
    float g = a + gat_bias[tid];
    gmean[(size_t)dst * CDIM + tid] = g;
    gs[tid] = g;
    __syncthreads();

    int t = tid >> 5, c = tid & 31;
    float v = gs[t * 32 + c] * Wp1[c];
#pragma unroll
    for (int off = 16; off; off >>= 1) v += __shfl_down(v, off, 32);
    if (c == 0) { float p = v + bp1[0]; ps[t] = p > 0.f ? p : 0.f; }
    __syncthreads();

    if (tid < PRED_LEN) {
        float acc = bp3[tid];
#pragma unroll
        for (int tt = 0; tt < 12; tt++) acc += Wp3[tid * 12 + tt] * ps[tt];
        acc = acc > 0.f ? acc : 0.f;
        size_t oi = (size_t)dst * PRED_LEN + tid;
        if (*flag) ((__hip_bfloat16*)out_pred)[oi] = __float2bfloat16(acc);
        else       ((float*)out_pred)[oi] = acc;
    }
}

__global__ __launch_bounds__(384) void pool_kernel(
    const float* __restrict__ gmean,
    unsigned* __restrict__ pooled_enc)
{
    int b = blockIdx.x, ch = blockIdx.y;
    int tid = threadIdx.x;
    const float* base = gmean + ((size_t)b * 1024 + ch * 64) * CDIM + tid;
    float m = -3.4e38f;
    for (int i = 0; i < 64; i++)
        m = fmaxf(m, base[(size_t)i * CDIM]);
    atomicMax(&pooled_enc[b * CDIM + tid], enc_f(m));
}

__global__ __launch_bounds__(384) void cls_kernel(
    const int* __restrict__ flag,
    const unsigned* __restrict__ pooled_enc,
    const float* __restrict__ Wc1, const float* __restrict__ bc1,
    const float* __restrict__ Wc2, const float* __restrict__ bc2,
    void* __restrict__ out_base)
{
    int b = blockIdx.x, t = threadIdx.x;
    __shared__ float l1[32];
    if (t < 32) l1[t] = bc1[t];
    __syncthreads();
    float v = dec_f(pooled_enc[b * CDIM + t]);
#pragma unroll
    for (int i = 0; i < 32; i++) {
        float p = v * Wc1[i * CDIM + t];
#pragma unroll
        for (int off = 32; off; off >>= 1) p += __shfl_down(p, off, 64);
        if ((t & 63) == 0) atomicAdd(&l1[i], p);
    }
    __syncthreads();
    if (t == 0) {
        float l0 = bc2[0], l1v = bc2[1];
#pragma unroll
        for (int ii = 0; ii < 32; ii++) {
            l0  += Wc2[ii] * l1[ii];
            l1v += Wc2[32 + ii] * l1[ii];
        }
        float m = fmaxf(l0, l1v);
        float e0 = expf(l0 - m), e1 = expf(l1v - m);
        float s = e0 + e1;
        if (*flag) {
            __hip_bfloat16* ob = (__hip_bfloat16*)out_base;
            ob[OUT_LABEL_OFF + b * 2 + 0] = __float2bfloat16(e0 / s);
            ob[OUT_LABEL_OFF + b * 2 + 1] = __float2bfloat16(e1 / s);
        } else {
            float* of = (float*)out_base;
            of[OUT_LABEL_OFF + b * 2 + 0] = e0 / s;
            of[OUT_LABEL_OFF + b * 2 + 1] = e1 / s;
        }
    }
}

extern "C" void kernel_launch(void* const* d_in, const int* in_sizes, int n_in,
                              void* d_out, int out_size, void* d_ws, size_t ws_size,
                              hipStream_t stream) {
    float* W = (float*)d_ws;
    int* flag = (int*)(W + O_FLAG);
    const int* edge_index = (const int*)d_in[1];

    fill_detect<<<236, 256, 0, stream>>>(
        (const unsigned short*)d_in[5], flag, W);
    convert_all<<<(CONV_TOTAL + 255) / 256, 256, 0, stream>>>(
        flag,
        d_in[0], d_in[5], d_in[6], d_in[7], d_in[8],
        d_in[9], d_in[10], d_in[11], d_in[12], d_in[13],
        d_in[14], d_in[15], d_in[16], d_in[17], d_in[18],
        d_in[19], d_in[20], d_in[21], d_in[22], d_in[2],
        W, (unsigned short*)(W + O_WGATB));

    gru_kernel<<<N_NODES / GNODES, 384, 0, stream>>>(
        W + O_X, W + O_WIH, W + O_WHH, W + O_BIH, W + O_BHH,
        (unsigned short*)(W + O_GATB));
    gemm_mfma<<<dim3(N_NODES / 128, NHC / 128), 256, 0, stream>>>(
        (const unsigned short*)(W + O_GATB),
        (const unsigned short*)(W + O_WGATB),
        (unsigned short*)(W + O_HFEAT));
    att_score_kernel<<<(N_NODES * 3) / 4 + 1, 256, 0, stream>>>(
        (const unsigned short*)(W + O_HFEAT), W + O_ATTS, W + O_ATTD,
        W + O_WEDGE, W + O_ATTE,
        W + O_ASRC, W + O_ADST, W + O_KH);
    edge_score_kernel<<<3 * E_EDGES / 256, 256, 0, stream>>>(
        edge_index, W + O_EATTR, W + O_ASRC, W + O_ADST, W + O_KH,
        W + O_ARAW, (unsigned*)(W + O_AMAX), (int*)(W + O_DEG));
    scan_kernel<<<1, 256, 0, stream>>>(
        (const int*)(W + O_DEG), (int*)(W + O_ROWST), (int*)(W + O_CURS));
    edge_exp_kernel<<<3 * E_EDGES / 256, 256, 0, stream>>>(
        edge_index, W + O_ARAW, (const unsigned*)(W + O_AMAX),
        W + O_WEXP, W + O_DENOM, (int*)(W + O_CURS), (int*)(W + O_CSRE));
    aggregate_fused<<<N_NODES, 384, 0, stream>>>(
        flag, edge_index, (const unsigned short*)(W + O_HFEAT),
        W + O_WEXP, W + O_DENOM,
        (const int*)(W + O_ROWST), (const int*)(W + O_DEG),
        (const int*)(W + O_CSRE),
        W + O_GBIAS, W + O_WP1, W + O_BP1, W + O_WP3, W + O_BP3,
        W + O_GMEAN, d_out);
    pool_kernel<<<dim3(8, 16), 384, 0, stream>>>(
        W + O_GMEAN, (unsigned*)(W + O_POOLED));
    cls_kernel<<<8, 384, 0, stream>>>(
        flag, (const unsigned*)(W + O_POOLED),
        W + O_WC1, W + O_BC1, W + O_WC2, W + O_BC2, d_out);
}

// Round 8
// 252.247 us; speedup vs baseline: 1.0943x; 1.0943x over previous
//
#include <hip/hip_runtime.h>
#include <hip/hip_bf16.h>

#define N_NODES 8192
#define E_EDGES 65536
#define HEADS 3
#define CDIM 384
#define NHC 1152
#define T_STEPS 12
#define D_IN 16
#define HID 32
#define PRED_LEN 6
#define OUT_LABEL_OFF 49152   // N_NODES*PRED_LEN elements

#define O_X        0u
#define O_WIH      1572864u
#define O_WHH      1574400u
#define O_BIH      1577472u
#define O_BHH      1577568u
#define O_WGAT     1577664u
#define O_ATTS     2020032u
#define O_ATTD     2021184u
#define O_WEDGE    2022336u
#define O_ATTE     2023488u
#define O_GBIAS    2024640u
#define O_WP1      2025024u
#define O_BP1      2025056u
#define O_WP3      2025057u
#define O_BP3      2025129u
#define O_WC1      2025135u
#define O_BC1      2037423u
#define O_WC2      2037455u
#define O_BC2      2037519u
#define O_EATTR    2037521u
#define CONV_TOTAL 2103057u

#define O_GATIN    2103072u
#define O_GATB     O_GATIN               // bf16 gat_in [N,384]
#define O_WGATB    (O_GATIN + 1572864u)  // bf16 Wgat [1152,384]
#define O_DEG      (O_GATIN + 1794048u)  // int [8192]
#define O_ROWST    (O_GATIN + 1802240u)  // int [8192]
#define O_CURS     (O_GATIN + 1810432u)  // int [8192]
#define O_CSRE     (O_GATIN + 1818624u)  // int [65536]
#define O_HFEAT    5248800u              // bf16 h_feat [N,1152]
#define O_ASRC     14685984u
#define O_ADST     14710560u
#define O_ARAW     14735136u
#define O_WEXP     14931744u
#define O_AMAX     15128352u
#define O_DENOM    15152928u
#define O_GMEAN    15177504u
#define O_POOLED   18323232u
#define O_KH       18326304u
#define O_FLAG     18326307u

typedef __attribute__((ext_vector_type(8))) short short8;
typedef __attribute__((ext_vector_type(4))) float floatx4;

__device__ __forceinline__ float b2f(unsigned short u) {
    return __uint_as_float(((unsigned)u) << 16);
}
__device__ __forceinline__ unsigned short f2b(float f) {
    __hip_bfloat16 b = __float2bfloat16(f);
    return *(unsigned short*)&b;
}
__device__ __forceinline__ short f2bs(float f) {
    __hip_bfloat16 b = __float2bfloat16(f);
    return *(short*)&b;
}
__device__ __forceinline__ unsigned enc_f(float f) {
    unsigned u = __float_as_uint(f);
    return (u & 0x80000000u) ? ~u : (u | 0x80000000u);
}
__device__ __forceinline__ float dec_f(unsigned e) {
    return __uint_as_float((e & 0x80000000u) ? (e & 0x7FFFFFFFu) : ~e);
}
__device__ __forceinline__ float fast_rcp(float x) {
    return __builtin_amdgcn_rcpf(x);
}

// ------------------------------------------------ fill (zero regions) + dtype detect
__global__ __launch_bounds__(256) void fill_detect(
    const unsigned short* __restrict__ wih_raw,
    int* __restrict__ flag,
    float* __restrict__ W)
{
    if (blockIdx.x == 0 && threadIdx.x < 64) {
        int lane = threadIdx.x;
        int cnt = 0;
#pragma unroll
        for (int i = 0; i < 8; i++) {
            unsigned short h = wih_raw[(lane * 8 + i) * 2];
            int e = (h >> 7) & 0xFF;
            if (e >= 100 && e <= 127) cnt++;
        }
#pragma unroll
        for (int off = 32; off; off >>= 1) cnt += __shfl_down(cnt, off, 64);
        if (lane == 0) *flag = (cnt >= 300) ? 1 : 0;
    }
    unsigned idx = blockIdx.x * 256 + threadIdx.x;
    if      (idx < 24576u) W[O_AMAX  + idx] = 0.f;
    else if (idx < 49152u) W[O_DENOM + idx - 24576u] = 0.f;
    else if (idx < 52224u) W[O_POOLED + idx - 49152u] = 0.f;
    else if (idx < 60416u) ((int*)(W + O_DEG))[idx - 52224u] = 0;
}

// ------------------------------------------------ convert all inputs; Wgat branch emits bf16
__global__ __launch_bounds__(256) void convert_all(
    const int* __restrict__ flag,
    const void* x, const void* Wih, const void* Whh, const void* bih, const void* bhh,
    const void* Wgat, const void* atts, const void* attd, const void* Wedge, const void* atte,
    const void* gbias, const void* Wp1, const void* bp1, const void* Wp3, const void* bp3,
    const void* Wc1, const void* bc1, const void* Wc2, const void* bc2, const void* eattr,
    float* __restrict__ dst, unsigned short* __restrict__ wgatb)
{
    unsigned idx = blockIdx.x * 256 + threadIdx.x;
    if (idx >= CONV_TOTAL) return;
    if (idx >= O_WGAT && idx < O_ATTS) {
        unsigned off = idx - O_WGAT;
        wgatb[off] = (*flag) ? ((const unsigned short*)Wgat)[off]
                             : f2b(((const float*)Wgat)[off]);
        return;
    }
    const void* src; unsigned off;
    if      (idx < O_WIH)   { src = x;     off = idx - O_X; }
    else if (idx < O_WHH)   { src = Wih;   off = idx - O_WIH; }
    else if (idx < O_BIH)   { src = Whh;   off = idx - O_WHH; }
    else if (idx < O_BHH)   { src = bih;   off = idx - O_BIH; }
    else if (idx < O_WGAT)  { src = bhh;   off = idx - O_BHH; }
    else if (idx < O_ATTD)  { src = atts;  off = idx - O_ATTS; }
    else if (idx < O_WEDGE) { src = attd;  off = idx - O_ATTD; }
    else if (idx < O_ATTE)  { src = Wedge; off = idx - O_WEDGE; }
    else if (idx < O_GBIAS) { src = atte;  off = idx - O_ATTE; }
    else if (idx < O_WP1)   { src = gbias; off = idx - O_GBIAS; }
    else if (idx < O_BP1)   { src = Wp1;   off = idx - O_WP1; }
    else if (idx < O_BP3)   { src = (idx == O_BP1) ? bp1 : Wp3; off = (idx == O_BP1) ? 0 : idx - O_WP3; }
    else if (idx < O_WC1)   { src = bp3;   off = idx - O_BP3; }
    else if (idx < O_BC1)   { src = Wc1;   off = idx - O_WC1; }
    else if (idx < O_WC2)   { src = bc1;   off = idx - O_BC1; }
    else if (idx < O_BC2)   { src = Wc2;   off = idx - O_WC2; }
    else if (idx < O_EATTR) { src = bc2;   off = idx - O_BC2; }
    else                    { src = eattr; off = idx - O_EATTR; }
    float v = (*flag) ? b2f(((const unsigned short*)src)[off])
                      : ((const float*)src)[off];
    dst[idx] = v;
}

// ------------------------------------------------ MFMA GRU: one wave = 16 nodes, no barriers.
// Per t: gate preacts via 12x mfma_f32_16x16x32_bf16 (A=weights[m=row,k=i],
// B=h/x[k,n=node]); C[m=row][n=node] -> lane holds node=lane&15, rows 4q+reg.
// h re-enters B-layout via 1.25KB LDS (stride-40 shorts, 2-way-max banks).
__global__ __launch_bounds__(64, 1) void gru_kernel(
    const float* __restrict__ W,          // workspace f32 base
    unsigned short* __restrict__ gat_b)   // [N,384] bf16
{
    __shared__ short hbuf[16 * 40];
    int lane = threadIdx.x;
    int q = lane >> 4, nl = lane & 15;
    int n0 = blockIdx.x * 16;
    int n = n0 + nl;

    const float* W_wih = W + O_WIH;
    const float* W_whh = W + O_WHH;
    const float* W_bih = W + O_BIH;
    const float* W_bhh = W + O_BHH;
    const float* W_x   = W + O_X;

    // weight fragments: A[m = c*16 + nl][k = 8q + r]
    short8 wh[6], wi[6];
#pragma unroll
    for (int c = 0; c < 6; c++) {
        int row = c * 16 + nl;
#pragma unroll
        for (int r = 0; r < 8; r++) {
            wh[c][r] = f2bs(W_whh[row * 32 + 8 * q + r]);
            int k = 8 * q + r;
            wi[c][r] = (k < 16) ? f2bs(W_wih[row * 16 + k]) : (short)0;
        }
    }
    // per-lane biases for j = c*16 + 4q + reg
    float br[8], bz[8], bni[8], bnh[8];
#pragma unroll
    for (int idx = 0; idx < 8; idx++) {
        int c = idx >> 2, r = idx & 3;
        int j = c * 16 + 4 * q + r;
        br[idx]  = W_bih[j] + W_bhh[j];
        bz[idx]  = W_bih[32 + j] + W_bhh[32 + j];
        bni[idx] = W_bih[64 + j];
        bnh[idx] = W_bhh[64 + j];
    }

    floatx4 zf = {0.f, 0.f, 0.f, 0.f};
    short8 zs; 
#pragma unroll
    for (int r = 0; r < 8; r++) zs[r] = 0;

    float hprev[8];
#pragma unroll
    for (int i = 0; i < 8; i++) hprev[i] = 0.f;
    short8 hfrag = zs;

    for (int t = 0; t < T_STEPS; t++) {
        // x fragment: B[k = 8q+r][n] = x[n][t*16 + k], zero for k>=16
        short8 xf = zs;
        if (q < 2) {
            const float* xp = W_x + (size_t)n * 192 + t * 16 + 8 * q;
            float4 xa = *(const float4*)xp;
            float4 xb = *(const float4*)(xp + 4);
            xf[0] = f2bs(xa.x); xf[1] = f2bs(xa.y); xf[2] = f2bs(xa.z); xf[3] = f2bs(xa.w);
            xf[4] = f2bs(xb.x); xf[5] = f2bs(xb.y); xf[6] = f2bs(xb.z); xf[7] = f2bs(xb.w);
        }

        floatx4 aR0 = __builtin_amdgcn_mfma_f32_16x16x32_bf16(wi[0], xf, zf, 0, 0, 0);
        aR0 = __builtin_amdgcn_mfma_f32_16x16x32_bf16(wh[0], hfrag, aR0, 0, 0, 0);
        floatx4 aR1 = __builtin_amdgcn_mfma_f32_16x16x32_bf16(wi[1], xf, zf, 0, 0, 0);
        aR1 = __builtin_amdgcn_mfma_f32_16x16x32_bf16(wh[1], hfrag, aR1, 0, 0, 0);
        floatx4 aZ0 = __builtin_amdgcn_mfma_f32_16x16x32_bf16(wi[2], xf, zf, 0, 0, 0);
        aZ0 = __builtin_amdgcn_mfma_f32_16x16x32_bf16(wh[2], hfrag, aZ0, 0, 0, 0);
        floatx4 aZ1 = __builtin_amdgcn_mfma_f32_16x16x32_bf16(wi[3], xf, zf, 0, 0, 0);
        aZ1 = __builtin_amdgcn_mfma_f32_16x16x32_bf16(wh[3], hfrag, aZ1, 0, 0, 0);
        floatx4 aNI0 = __builtin_amdgcn_mfma_f32_16x16x32_bf16(wi[4], xf, zf, 0, 0, 0);
        floatx4 aNI1 = __builtin_amdgcn_mfma_f32_16x16x32_bf16(wi[5], xf, zf, 0, 0, 0);
        floatx4 aNH0 = __builtin_amdgcn_mfma_f32_16x16x32_bf16(wh[4], hfrag, zf, 0, 0, 0);
        floatx4 aNH1 = __builtin_amdgcn_mfma_f32_16x16x32_bf16(wh[5], hfrag, zf, 0, 0, 0);

        // combine (lane: node=nl, j = c*16 + 4q + reg) and write h to LDS
#pragma unroll
        for (int idx = 0; idx < 8; idx++) {
            int c = idx >> 2, r = idx & 3;
            float vR = (c ? aR1[r] : aR0[r]) + br[idx];
            float vZ = (c ? aZ1[r] : aZ0[r]) + bz[idx];
            float vNI = (c ? aNI1[r] : aNI0[r]) + bni[idx];
            float vNH = (c ? aNH1[r] : aNH0[r]) + bnh[idx];
            float rr = fast_rcp(1.f + __expf(-vR));
            float zz = fast_rcp(1.f + __expf(-vZ));
            float pre = vNI + rr * vNH;
            float e2 = __expf(2.f * pre);
            float nn = 1.f - 2.f * fast_rcp(e2 + 1.f);
            float h = (1.f - zz) * nn + zz * hprev[idx];
            hprev[idx] = h;
            int j = c * 16 + 4 * q + r;
            hbuf[nl * 40 + j] = f2bs(h);
        }
        // next-step h B-fragment: lane holds h[node=nl][i = 8q..8q+7]
        hfrag = *(short8*)&hbuf[nl * 40 + 8 * q];
        // coalesced global store of this timestep's h
        int sn = lane >> 2, jg = (lane & 3) * 8;
        short8 hv = *(short8*)&hbuf[sn * 40 + jg];
        *(short8*)(gat_b + (size_t)(n0 + sn) * 384 + t * 32 + jg) = hv;
    }
}

// ------------------------------------------------ MFMA GEMM, bf16 output
__global__ __launch_bounds__(256) void gemm_mfma(
    const unsigned short* __restrict__ Ab,
    const unsigned short* __restrict__ Bb,
    unsigned short* __restrict__ Cb)
{
    __shared__ unsigned short sA[128][40];
    __shared__ unsigned short sB[128][40];
    int tid = threadIdx.x;
    int wave = tid >> 6, lane = tid & 63;
    int wm = (wave >> 1) * 64, wn = (wave & 1) * 64;
    int m0 = blockIdx.x * 128, n0 = blockIdx.y * 128;

    int r0 = tid >> 2;
    int c8 = (tid & 3) * 8;

    floatx4 acc[4][4];
#pragma unroll
    for (int i = 0; i < 4; i++)
#pragma unroll
        for (int j = 0; j < 4; j++) acc[i][j] = 0;

    int ml = lane & 15, kq = (lane >> 4) * 8;

    for (int k0 = 0; k0 < 384; k0 += 32) {
        short8 a0 = *(const short8*)(Ab + (size_t)(m0 + r0) * 384 + k0 + c8);
        short8 a1 = *(const short8*)(Ab + (size_t)(m0 + r0 + 64) * 384 + k0 + c8);
        short8 b0 = *(const short8*)(Bb + (size_t)(n0 + r0) * 384 + k0 + c8);
        short8 b1 = *(const short8*)(Bb + (size_t)(n0 + r0 + 64) * 384 + k0 + c8);

        __syncthreads();
        *(short8*)(&sA[r0][c8])      = a0;
        *(short8*)(&sA[r0 + 64][c8]) = a1;
        *(short8*)(&sB[r0][c8])      = b0;
        *(short8*)(&sB[r0 + 64][c8]) = b1;
        __syncthreads();

        short8 af[4], bf[4];
#pragma unroll
        for (int i = 0; i < 4; i++)
            af[i] = *(const short8*)(&sA[wm + i * 16 + ml][kq]);
#pragma unroll
        for (int j = 0; j < 4; j++)
            bf[j] = *(const short8*)(&sB[wn + j * 16 + ml][kq]);
#pragma unroll
        for (int i = 0; i < 4; i++)
#pragma unroll
            for (int j = 0; j < 4; j++)
                acc[i][j] = __builtin_amdgcn_mfma_f32_16x16x32_bf16(af[i], bf[j], acc[i][j], 0, 0, 0);
    }

    int cn = lane & 15, rq = (lane >> 4) * 4;
#pragma unroll
    for (int i = 0; i < 4; i++)
#pragma unroll
        for (int j = 0; j < 4; j++)
#pragma unroll
            for (int r = 0; r < 4; r++)
                Cb[(size_t)(m0 + wm + i * 16 + rq + r) * NHC + n0 + wn + j * 16 + cn] = f2b(acc[i][j][r]);
}

// ------------------------------------------------ node attention scores (+ Kh in extra block)
__global__ __launch_bounds__(256) void att_score_kernel(
    const unsigned short* __restrict__ h_bf,
    const float* __restrict__ att_src,
    const float* __restrict__ att_dst,
    const float* __restrict__ Wedge,
    const float* __restrict__ att_edge,
    float* __restrict__ a_src, float* __restrict__ a_dst,
    float* __restrict__ Kh)
{
    if (blockIdx.x == (N_NODES * 3) / 4) {
        if (threadIdx.x < 192) {
            int hd = threadIdx.x >> 6, lane = threadIdx.x & 63;
            float s = 0.f;
#pragma unroll
            for (int qq = 0; qq < 6; qq++) {
                int c = lane + qq * 64;
                s += Wedge[hd * CDIM + c] * att_edge[hd * CDIM + c];
            }
#pragma unroll
            for (int off = 32; off; off >>= 1) s += __shfl_down(s, off, 64);
            if (lane == 0) Kh[hd] = s;
        }
        return;
    }
    int w = (blockIdx.x * 256 + threadIdx.x) >> 6;
    int lane = threadIdx.x & 63;
    int n = w / 3, hd = w % 3;
    const unsigned short* hrow = h_bf + (size_t)n * NHC + hd * CDIM;
    float s0 = 0.f, s1 = 0.f;
#pragma unroll
    for (int qq = 0; qq < 6; qq++) {
        int c = lane + qq * 64;
        float hv = b2f(hrow[c]);
        s0 += hv * att_src[hd * CDIM + c];
        s1 += hv * att_dst[hd * CDIM + c];
    }
#pragma unroll
    for (int off = 32; off; off >>= 1) {
        s0 += __shfl_down(s0, off, 64);
        s1 += __shfl_down(s1, off, 64);
    }
    if (lane == 0) { a_src[n * 3 + hd] = s0; a_dst[n * 3 + hd] = s1; }
}

__global__ __launch_bounds__(256) void edge_score_kernel(
    const int* __restrict__ edge_index,
    const float* __restrict__ edge_attr,
    const float* __restrict__ a_src, const float* __restrict__ a_dst,
    const float* __restrict__ Kh,
    float* __restrict__ a_raw, unsigned* __restrict__ amax_enc,
    int* __restrict__ deg)
{
    int tid = blockIdx.x * 256 + threadIdx.x;
    int hd = tid >> 16;
    int e = tid & (E_EDGES - 1);
    int src = edge_index[e];
    int dst = edge_index[E_EDGES + e];
    float a = a_src[src * 3 + hd] + a_dst[dst * 3 + hd] + edge_attr[e] * Kh[hd];
    a = a > 0.f ? a : 0.2f * a;
    a_raw[hd * E_EDGES + e] = a;
    atomicMax(&amax_enc[dst * 3 + hd], enc_f(a));
    if (hd == 0) atomicAdd(&deg[dst], 1);
}

// parallel exclusive scan of deg[8192] (single block, shfl_up wave scans)
__global__ __launch_bounds__(256) void scan_kernel(
    const int* __restrict__ deg, int* __restrict__ rowstart, int* __restrict__ cursor)
{
    __shared__ int wtot[4];
    int t = threadIdx.x;
    int lane = t & 63, wv = t >> 6;
    int l[32], s = 0;
#pragma unroll
    for (int i = 0; i < 32; i++) { l[i] = deg[t * 32 + i]; s += l[i]; }
    int sc = s;
#pragma unroll
    for (int off = 1; off <= 32; off <<= 1) {
        int v = __shfl_up(sc, off, 64);
        if (lane >= off) sc += v;
    }
    if (lane == 63) wtot[wv] = sc;
    __syncthreads();
    int woff = 0;
#pragma unroll
    for (int w = 0; w < 4; w++) if (w < wv) woff += wtot[w];
    int b = woff + sc - s;
#pragma unroll
    for (int i = 0; i < 32; i++) {
        rowstart[t * 32 + i] = b;
        cursor[t * 32 + i] = b;
        b += l[i];
    }
}

__global__ __launch_bounds__(256) void edge_exp_kernel(
    const int* __restrict__ edge_index,
    const float* __restrict__ a_raw, const unsigned* __restrict__ amax_enc,
    float* __restrict__ w_exp, float* __restrict__ denom,
    int* __restrict__ cursor, int* __restrict__ csr_e)
{
    int tid = blockIdx.x * 256 + threadIdx.x;
    int hd = tid >> 16;
    int e = tid & (E_EDGES - 1);
    int dst = edge_index[E_EDGES + e];
    float m = dec_f(amax_enc[dst * 3 + hd]);
    float w = expf(a_raw[hd * E_EDGES + e] - m);
    w_exp[hd * E_EDGES + e] = w;
    unsafeAtomicAdd(&denom[dst * 3 + hd], w);
    if (hd == 0) {
        int pos = atomicAdd(&cursor[dst], 1);
        csr_e[pos] = e;
    }
}

// CSR aggregation fused with head-mean+bias, predictor MLP, out_pred write.
__global__ __launch_bounds__(384) void aggregate_fused(
    const int* __restrict__ flag,
    const int* __restrict__ edge_index,
    const unsigned short* __restrict__ h_bf,
    const float* __restrict__ w_exp, const float* __restrict__ denom,
    const int* __restrict__ rowstart, const int* __restrict__ deg,
    const int* __restrict__ csr_e,
    const float* __restrict__ gat_bias,
    const float* __restrict__ Wp1, const float* __restrict__ bp1,
    const float* __restrict__ Wp3, const float* __restrict__ bp3,
    float* __restrict__ gmean,
    void* __restrict__ out_pred)
{
    int dst = blockIdx.x;
    int s = rowstart[dst], d = deg[dst];
    int tid = threadIdx.x;
    const float third = 1.f / 3.f;
    float inv0 = third / (denom[dst * 3 + 0] + 1e-16f);
    float inv1 = third / (denom[dst * 3 + 1] + 1e-16f);
    float inv2 = third / (denom[dst * 3 + 2] + 1e-16f);
    __shared__ int ssrc[64];
    __shared__ float sc0[64], sc1[64], sc2[64];
    __shared__ float gs[384];
    __shared__ float ps[12];
    float a = 0.f;
    for (int ch = 0; ch < d; ch += 64) {
        int m = d - ch; if (m > 64) m = 64;
        __syncthreads();
        if (tid < m) {
            int e = csr_e[s + ch + tid];
            ssrc[tid] = edge_index[e];
            sc0[tid] = w_exp[e] * inv0;
            sc1[tid] = w_exp[E_EDGES + e] * inv1;
            sc2[tid] = w_exp[2 * E_EDGES + e] * inv2;
        }
        __syncthreads();
        for (int i = 0; i < m; i++) {
            const unsigned short* hs = h_bf + (size_t)ssrc[i] * NHC;
            a += sc0[i] * b2f(hs[tid]) + sc1[i] * b2f(hs[tid + CDIM]) + sc2[i] * b2f(hs[tid + 2 * CDIM]);
        }
    }
    float g = a + gat_bias[tid];
    gmean[(size_t)dst * CDIM + tid] = g;
    gs[tid] = g;
    __syncthreads();

    int t = tid >> 5, c = tid & 31;
    float v = gs[t * 32 + c] * Wp1[c];
#pragma unroll
    for (int off = 16; off; off >>= 1) v += __shfl_down(v, off, 32);
    if (c == 0) { float p = v + bp1[0]; ps[t] = p > 0.f ? p : 0.f; }
    __syncthreads();

    if (tid < PRED_LEN) {
        float acc = bp3[tid];
#pragma unroll
        for (int tt = 0; tt < 12; tt++) acc += Wp3[tid * 12 + tt] * ps[tt];
        acc = acc > 0.f ? acc : 0.f;
        size_t oi = (size_t)dst * PRED_LEN + tid;
        if (*flag) ((__hip_bfloat16*)out_pred)[oi] = __float2bfloat16(acc);
        else       ((float*)out_pred)[oi] = acc;
    }
}

__global__ __launch_bounds__(384) void pool_kernel(
    const float* __restrict__ gmean,
    unsigned* __restrict__ pooled_enc)
{
    int b = blockIdx.x, ch = blockIdx.y;
    int tid = threadIdx.x;
    const float* base = gmean + ((size_t)b * 1024 + ch * 64) * CDIM + tid;
    float m = -3.4e38f;
    for (int i = 0; i < 64; i++)
        m = fmaxf(m, base[(size_t)i * CDIM]);
    atomicMax(&pooled_enc[b * CDIM + tid], enc_f(m));
}

__global__ __launch_bounds__(384) void cls_kernel(
    const int* __restrict__ flag,
    const unsigned* __restrict__ pooled_enc,
    const float* __restrict__ Wc1, const float* __restrict__ bc1,
    const float* __restrict__ Wc2, const float* __restrict__ bc2,
    void* __restrict__ out_base)
{
    int b = blockIdx.x, t = threadIdx.x;
    __shared__ float l1[32];
    if (t < 32) l1[t] = bc1[t];
    __syncthreads();
    float v = dec_f(pooled_enc[b * CDIM + t]);
#pragma unroll
    for (int i = 0; i < 32; i++) {
        float p = v * Wc1[i * CDIM + t];
#pragma unroll
        for (int off = 32; off; off >>= 1) p += __shfl_down(p, off, 64);
        if ((t & 63) == 0) atomicAdd(&l1[i], p);
    }
    __syncthreads();
    if (t == 0) {
        float l0 = bc2[0], l1v = bc2[1];
#pragma unroll
        for (int ii = 0; ii < 32; ii++) {
            l0  += Wc2[ii] * l1[ii];
            l1v += Wc2[32 + ii] * l1[ii];
        }
        float m = fmaxf(l0, l1v);
        float e0 = expf(l0 - m), e1 = expf(l1v - m);
        float s = e0 + e1;
        if (*flag) {
            __hip_bfloat16* ob = (__hip_bfloat16*)out_base;
            ob[OUT_LABEL_OFF + b * 2 + 0] = __float2bfloat16(e0 / s);
            ob[OUT_LABEL_OFF + b * 2 + 1] = __float2bfloat16(e1 / s);
        } else {
            float* of = (float*)out_base;
            of[OUT_LABEL_OFF + b * 2 + 0] = e0 / s;
            of[OUT_LABEL_OFF + b * 2 + 1] = e1 / s;
        }
    }
}

extern "C" void kernel_launch(void* const* d_in, const int* in_sizes, int n_in,
                              void* d_out, int out_size, void* d_ws, size_t ws_size,
                              hipStream_t stream) {
    float* W = (float*)d_ws;
    int* flag = (int*)(W + O_FLAG);
    const int* edge_index = (const int*)d_in[1];

    fill_detect<<<236, 256, 0, stream>>>(
        (const unsigned short*)d_in[5], flag, W);
    convert_all<<<(CONV_TOTAL + 255) / 256, 256, 0, stream>>>(
        flag,
        d_in[0], d_in[5], d_in[6], d_in[7], d_in[8],
        d_in[9], d_in[10], d_in[11], d_in[12], d_in[13],
        d_in[14], d_in[15], d_in[16], d_in[17], d_in[18],
        d_in[19], d_in[20], d_in[21], d_in[22], d_in[2],
        W, (unsigned short*)(W + O_WGATB));

    gru_kernel<<<N_NODES / 16, 64, 0, stream>>>(
        W, (unsigned short*)(W + O_GATB));
    gemm_mfma<<<dim3(N_NODES / 128, NHC / 128), 256, 0, stream>>>(
        (const unsigned short*)(W + O_GATB),
        (const unsigned short*)(W + O_WGATB),
        (unsigned short*)(W + O_HFEAT));
    att_score_kernel<<<(N_NODES * 3) / 4 + 1, 256, 0, stream>>>(
        (const unsigned short*)(W + O_HFEAT), W + O_ATTS, W + O_ATTD,
        W + O_WEDGE, W + O_ATTE,
        W + O_ASRC, W + O_ADST, W + O_KH);
    edge_score_kernel<<<3 * E_EDGES / 256, 256, 0, stream>>>(
        edge_index, W + O_EATTR, W + O_ASRC, W + O_ADST, W + O_KH,
        W + O_ARAW, (unsigned*)(W + O_AMAX), (int*)(W + O_DEG));
    scan_kernel<<<1, 256, 0, stream>>>(
        (const int*)(W + O_DEG), (int*)(W + O_ROWST), (int*)(W + O_CURS));
    edge_exp_kernel<<<3 * E_EDGES / 256, 256, 0, stream>>>(
        edge_index, W + O_ARAW, (const unsigned*)(W + O_AMAX),
        W + O_WEXP, W + O_DENOM, (int*)(W + O_CURS), (int*)(W + O_CSRE));
    aggregate_fused<<<N_NODES, 384, 0, stream>>>(
        flag, edge_index, (const unsigned short*)(W + O_HFEAT),
        W + O_WEXP, W + O_DENOM,
        (const int*)(W + O_ROWST), (const int*)(W + O_DEG),
        (const int*)(W + O_CSRE),
        W + O_GBIAS, W + O_WP1, W + O_BP1, W + O_WP3, W + O_BP3,
        W + O_GMEAN, d_out);
    pool_kernel<<<dim3(8, 16), 384, 0, stream>>>(
        W + O_GMEAN, (unsigned*)(W + O_POOLED));
    cls_kernel<<<8, 384, 0, stream>>>(
        flag, (const unsigned*)(W + O_POOLED),
        W + O_WC1, W + O_BC1, W + O_WC2, W + O_BC2, d_out);
}